// Round 24
// baseline (165.569 us; speedup 1.0000x reference)
//
#include <hip/hip_runtime.h>
#include <stdint.h>
#include <math.h>

#define NN 4096
#define DIN 1024
#define DOUT 512
#define ALPHA 0.2f

typedef __attribute__((ext_vector_type(8))) short short8;
typedef __attribute__((ext_vector_type(4))) float f32x4;

__device__ __forceinline__ unsigned short f2bf(float f) {
    uint32_t u = __float_as_uint(f);
    u += 0x7fffu + ((u >> 16) & 1u);
    return (unsigned short)(u >> 16);
}

__device__ __forceinline__ void async16(const void* g, void* l) {
    __builtin_amdgcn_global_load_lds(
        (const __attribute__((address_space(1))) uint32_t*)g,
        (__attribute__((address_space(3))) uint32_t*)l, 16, 0, 0);
}

__device__ __forceinline__ void spin_until(unsigned int* f, unsigned int tgt) {
    while (__hip_atomic_load(f, __ATOMIC_ACQUIRE, __HIP_MEMORY_SCOPE_AGENT) < tgt)
        __builtin_amdgcn_s_sleep(4);
}

__device__ __forceinline__ void signal_done(unsigned int* f) {
    __threadfence();
    __hip_atomic_fetch_add(f, 1u, __ATOMIC_RELEASE, __HIP_MEMORY_SCOPE_AGENT);
}

// ---------------- K1: mask | wt | wa | flag-zero (input-independent; 2560)
__global__ __launch_bounds__(256) void k_prep3(const float* __restrict__ adj,
    const float* __restrict__ W, const float* __restrict__ Wf,
    const float* __restrict__ a1, const float* __restrict__ a2,
    unsigned short* __restrict__ wt, float* __restrict__ wa1,
    float* __restrict__ wa2, unsigned short* __restrict__ bits16,
    unsigned int* flags) {
    int tid = threadIdx.x;
    if (blockIdx.x < 2048) {
        int row0 = blockIdx.x * 2;
        const float4* a0 = (const float4*)(adj + (size_t)row0 * NN);
        const float4* a1v = (const float4*)(adj + (size_t)(row0 + 1) * NN);
        float4 v0 = a0[tid];        float4 v1 = a0[tid + 256];
        float4 v2 = a0[tid + 512];  float4 v3 = a0[tid + 768];
        float4 v4 = a1v[tid];       float4 v5 = a1v[tid + 256];
        float4 v6 = a1v[tid + 512]; float4 v7 = a1v[tid + 768];
        __builtin_amdgcn_sched_barrier(0);   // all 8 loads issue first (rule #18)
        unsigned int m0 = 0, m1 = 0;
#define MB(M, V, J)                                            \
        M |= (((V).x != 0.f) ? 1u : 0u) << (4 * (J));          \
        M |= (((V).y != 0.f) ? 1u : 0u) << (4 * (J) + 1);      \
        M |= (((V).z != 0.f) ? 1u : 0u) << (4 * (J) + 2);      \
        M |= (((V).w != 0.f) ? 1u : 0u) << (4 * (J) + 3);
        MB(m0, v0, 0) MB(m0, v1, 1) MB(m0, v2, 2) MB(m0, v3, 3)
        MB(m1, v4, 0) MB(m1, v5, 1) MB(m1, v6, 2) MB(m1, v7, 3)
#undef MB
        bits16[(size_t)row0 * 256 + tid]       = (unsigned short)m0;
        bits16[(size_t)row0 * 256 + 256 + tid] = (unsigned short)m1;
    } else if (blockIdx.x < 2304) {
        if (blockIdx.x == 2048 && tid < 8) flags[tid] = 0;
        int idx = blockIdx.x - 2048;
        int bx = idx & 7, gy = idx >> 3;
        int n = bx * 64 + (tid & 63);
        int g = gy * 4 + (tid >> 6);          // k-granule 0..127
        float v[8];
#pragma unroll
        for (int j = 0; j < 8; ++j) v[j] = W[(size_t)(g * 8 + j) * DOUT + n];
        union { unsigned short u[8]; uint4 q; } pk;
#pragma unroll
        for (int j = 0; j < 8; ++j) pk.u[j] = f2bf(v[j]);
        int sw = (n >> 1) & 3;
        int p  = (g & ~3) | ((g & 3) ^ sw);
        *(uint4*)(wt + (size_t)n * DIN + p * 8) = pk.q;
    } else {
        int row  = (blockIdx.x - 2304) * 4 + (tid >> 6);
        int lane = tid & 63;
        const float* wr = Wf + (size_t)row * DOUT;
        float s1 = 0.f, s2 = 0.f;
        for (int k = lane; k < DOUT; k += 64) {
            float w = wr[k];
            s1 += w * a1[k];
            s2 += w * a2[k];
        }
        for (int off = 32; off; off >>= 1) {
            s1 += __shfl_down(s1, off);
            s2 += __shfl_down(s2, off);
        }
        if (lane == 0) { wa1[row] = s1; wa2[row] = s2; }
    }
}

// ---------------- K2: f1,f2 GEMV + x -> bf16 (pre-swizzled), wave per row
__global__ __launch_bounds__(256) void k_fx(const float* __restrict__ x,
    const float* __restrict__ wa1, const float* __restrict__ wa2,
    const float* __restrict__ b1, const float* __restrict__ b2,
    float* __restrict__ f1, float* __restrict__ f2,
    unsigned short* __restrict__ xb) {
    int row  = blockIdx.x * 4 + (threadIdx.x >> 6);
    int lane = threadIdx.x & 63;
    const float* xr = x + (size_t)row * DIN + lane * 16;
    float xv[16];
    *(float4*)&xv[0]  = *(const float4*)(xr);
    *(float4*)&xv[4]  = *(const float4*)(xr + 4);
    *(float4*)&xv[8]  = *(const float4*)(xr + 8);
    *(float4*)&xv[12] = *(const float4*)(xr + 12);
    __builtin_amdgcn_sched_barrier(0);   // all 4 loads in flight
    const float* w1 = wa1 + lane * 16;
    const float* w2 = wa2 + lane * 16;
    float s1 = 0.f, s2 = 0.f;
#pragma unroll
    for (int j = 0; j < 16; ++j) {
        s1 += xv[j] * w1[j];
        s2 += xv[j] * w2[j];
    }
    union { unsigned short u[8]; uint4 q; } pk0, pk1;
#pragma unroll
    for (int j = 0; j < 8; ++j) { pk0.u[j] = f2bf(xv[j]); pk1.u[j] = f2bf(xv[8 + j]); }
    int sw = (row >> 1) & 3;
    int g0 = lane * 2, g1 = lane * 2 + 1;
    int p0 = (g0 & ~3) | ((g0 & 3) ^ sw);
    int p1 = (g1 & ~3) | ((g1 & 3) ^ sw);
    unsigned short* xrow = xb + (size_t)row * DIN;
    *(uint4*)(xrow + p0 * 8) = pk0.q;
    *(uint4*)(xrow + p1 * 8) = pk1.q;
    for (int off = 32; off; off >>= 1) {
        s1 += __shfl_down(s1, off);
        s2 += __shfl_down(s2, off);
    }
    if (lane == 0) { f1[row] = s1 + b1[0]; f2[row] = s2 + b2[0]; }
}

// ---------------- K3: FUSED z | s | gemm with short spins.
// blocks [0,512):    z, 8 rows each -> signal flags[0]   (never spins)
// blocks [512,1024): spin flags[0]==512 (~z tail, short) -> s, 8 rows -> flags[1]
// blocks [1024,1536): gemm K-loop (no deps) -> spin flags[1]==512 -> epilogue
// Deadlock-free: LDS 24.6KB -> >=6 blocks/CU -> >=1536 slots; spinnable
// blocks (1024) < 1536, so z producers always have slots (G16-safe).
__global__ __launch_bounds__(256) void k_zsg(
    const unsigned long long* __restrict__ bits,
    const float* __restrict__ f1, const float* __restrict__ f2,
    float* __restrict__ rZ, float* __restrict__ sarr,
    const unsigned short* __restrict__ xb, const unsigned short* __restrict__ wt,
    unsigned int* flags, float* __restrict__ out) {
    __shared__ __align__(16) unsigned short As[3][64][32];
    __shared__ __align__(16) unsigned short Bs[3][64][32];
    int tid = threadIdx.x, b = blockIdx.x;
    int wid = tid >> 6, lane = tid & 63;

    if (b < 512) {
        // ---- z: 8 rows (wave per row, 2 passes) ----
#pragma unroll
        for (int st = 0; st < 2; ++st) {
            int row = b * 8 + st * 4 + wid;
            unsigned long long w = bits[(size_t)row * 64 + lane];
            float f1r = f1[row];
            float z = 0.f;
            while (w) {
                int bb = __builtin_ctzll(w);
                w &= w - 1;
                int j = 16 * lane + 4 * (bb >> 4) + 1024 * ((bb >> 2) & 3) + (bb & 3);
                float l = f1r + f2[j];
                z += __expf((l >= 0.f) ? l : ALPHA * l);
            }
            for (int off = 32; off; off >>= 1) z += __shfl_down(z, off);
            if (lane == 0) rZ[row] = 1.0f / z;
        }
        __syncthreads();
        if (tid == 0) signal_done(&flags[0]);
    } else if (b < 1024) {
        // ---- s: spin for z (short), then 8 rows ----
        if (tid == 0) spin_until(&flags[0], 512);
        __syncthreads();
#pragma unroll
        for (int st = 0; st < 2; ++st) {
            int row = (b - 512) * 8 + st * 4 + wid;
            unsigned long long w = bits[(size_t)row * 64 + lane];
            float f2r = f2[row];
            float sum = 0.f;
            while (w) {
                int bb = __builtin_ctzll(w);
                w &= w - 1;
                int j = 16 * lane + 4 * (bb >> 4) + 1024 * ((bb >> 2) & 3) + (bb & 3);
                float l = f1[j] + f2r;
                float e = (l >= 0.f) ? l : ALPHA * l;
                sum += __expf(e) * rZ[j];
            }
            for (int off = 32; off; off >>= 1) sum += __shfl_down(sum, off);
            if (lane == 0) {
                float l   = f1[row] + f2r;
                float e   = (l >= 0.f) ? l : ALPHA * l;
                float cjj = __expf(e) * rZ[row];
                sarr[row] = (cjj + 1.0f) / (1.5f + 0.5f * sum);
            }
        }
        __syncthreads();
        if (tid == 0) signal_done(&flags[1]);
    } else {
        // ---- gemm: K-loop first (needs only xb/wt), spin before epilogue ----
        int lid = b - 1024;                          // 0..511
        int xcd = lid & 7, idx = lid >> 3;
        int by = xcd * 8 + (idx & 7);
        int bx = idx >> 3;
        int bm = by * 64, bn = bx * 64;

        int wr = wid >> 1, wc = wid & 1;
        int srow = lane >> 2, sg = lane & 3;
        const unsigned short* ga0 = xb + (size_t)(bm + wid * 16 + srow) * DIN + sg * 8;
        const unsigned short* gb0 = wt + (size_t)(bn + wid * 16 + srow) * DIN + sg * 8;

        int r15 = lane & 15, gl = lane >> 4;
        int gofs = (gl ^ ((r15 >> 1) & 3)) * 8;

        f32x4 acc[2][2] = {};

#define STAGE(BUF, K0) do {                                              \
        async16(ga0 + (K0), &As[BUF][wid * 16][0]);                      \
        async16(gb0 + (K0), &Bs[BUF][wid * 16][0]);                      \
    } while (0)

#define COMPUTE(BUF) do {                                                \
        const unsigned short* pa = &As[BUF][wr * 32 + r15][gofs];        \
        const unsigned short* pb = &Bs[BUF][wc * 32 + r15][gofs];        \
        short8 af0 = *(const short8*)(pa);                               \
        short8 af1 = *(const short8*)(pa + 16 * 32);                     \
        short8 bf0 = *(const short8*)(pb);                               \
        short8 bf1 = *(const short8*)(pb + 16 * 32);                     \
        acc[0][0] = __builtin_amdgcn_mfma_f32_16x16x32_bf16(af0, bf0, acc[0][0], 0, 0, 0); \
        acc[0][1] = __builtin_amdgcn_mfma_f32_16x16x32_bf16(af0, bf1, acc[0][1], 0, 0, 0); \
        acc[1][0] = __builtin_amdgcn_mfma_f32_16x16x32_bf16(af1, bf0, acc[1][0], 0, 0, 0); \
        acc[1][1] = __builtin_amdgcn_mfma_f32_16x16x32_bf16(af1, bf1, acc[1][1], 0, 0, 0); \
    } while (0)

#define WAITBAR(N) do {                                                  \
        asm volatile("s_waitcnt vmcnt(" #N ")" ::: "memory");            \
        __builtin_amdgcn_sched_barrier(0);                               \
        __builtin_amdgcn_s_barrier();                                    \
        __builtin_amdgcn_sched_barrier(0);                               \
    } while (0)

        STAGE(0, 0);
        STAGE(1, 32);
        for (int t = 0; t < 30; ++t) {
            WAITBAR(2);
            COMPUTE(t % 3);
            STAGE((t + 2) % 3, (t + 2) * 32);
        }
        WAITBAR(2);
        COMPUTE(0);
        WAITBAR(0);
        COMPUTE(1);

        if (tid == 0) spin_until(&flags[1], 512);    // s ready (short spin)
        __syncthreads();

#pragma unroll
        for (int mi = 0; mi < 2; ++mi) {
            int crow0 = bm + wr * 32 + mi * 16 + gl * 4;
#pragma unroll
            for (int ni = 0; ni < 2; ++ni) {
                int ccol = bn + wc * 32 + ni * 16 + r15;
#pragma unroll
                for (int r = 0; r < 4; ++r) {
                    int row = crow0 + r;
                    float v = acc[mi][ni][r] * sarr[row];
                    out[(size_t)row * DOUT + ccol] = fmaxf(v, 0.f);
                }
            }
        }
#undef STAGE
#undef COMPUTE
#undef WAITBAR
    }
}

extern "C" void kernel_launch(void* const* d_in, const int* in_sizes, int n_in,
                              void* d_out, int out_size, void* d_ws, size_t ws_size,
                              hipStream_t stream) {
    const float* x   = (const float*)d_in[0];
    const float* adj = (const float*)d_in[1];
    const float* Wf  = (const float*)d_in[2];
    const float* a1  = (const float*)d_in[3];
    const float* b1  = (const float*)d_in[4];
    const float* a2  = (const float*)d_in[5];
    const float* b2  = (const float*)d_in[6];
    const float* W   = (const float*)d_in[7];
    float* out = (float*)d_out;

    char* w = (char*)d_ws;
    float* wa1 = (float*)(w + 0);
    float* wa2 = (float*)(w + 4096);
    float* f1  = (float*)(w + 16384);
    float* f2  = (float*)(w + 32768);
    float* rZ  = (float*)(w + 49152);
    float* s   = (float*)(w + 65536);
    unsigned int* flags = (unsigned int*)(w + 81920);
    unsigned short* bits16 = (unsigned short*)(w + 98304);           // 2 MB
    unsigned short* xb = (unsigned short*)(w + 2195456);             // 8 MB
    unsigned short* wt = (unsigned short*)(w + 10584064);            // 1 MB

    k_prep3<<<2560, 256, 0, stream>>>(adj, W, Wf, a1, a2, wt, wa1, wa2,
                                      bits16, flags);
    k_fx<<<1024, 256, 0, stream>>>(x, wa1, wa2, b1, b2, f1, f2, xb);
    k_zsg<<<1536, 256, 0, stream>>>((const unsigned long long*)bits16, f1, f2,
                                    rZ, s, xb, wt, flags, out);
}

// Round 25
// 43.430 us; speedup vs baseline: 3.8123x; 3.8123x over previous
//
#include <hip/hip_runtime.h>
#include <stdint.h>
#include <math.h>

#define NN 4096
#define DIN 1024
#define DOUT 512
#define ALPHA 0.2f

typedef __attribute__((ext_vector_type(8))) short short8;
typedef __attribute__((ext_vector_type(4))) float f32x4;

__device__ __forceinline__ unsigned short f2bf(float f) {
    uint32_t u = __float_as_uint(f);
    u += 0x7fffu + ((u >> 16) & 1u);
    return (unsigned short)(u >> 16);
}

__device__ __forceinline__ void async16(const void* g, void* l) {
    __builtin_amdgcn_global_load_lds(
        (const __attribute__((address_space(1))) uint32_t*)g,
        (__attribute__((address_space(3))) uint32_t*)l, 16, 0, 0);
}

// ---- proven bodies ----
__device__ __forceinline__ void mask4(const float* __restrict__ adj,
                                      unsigned short* __restrict__ bits16,
                                      int row0, int tid) {
    const float* a0 = adj + (size_t)row0 * NN;
    float4 v[16];
#pragma unroll
    for (int r = 0; r < 4; ++r)
#pragma unroll
        for (int i = 0; i < 4; ++i)
            v[r * 4 + i] = ((const float4*)(a0 + (size_t)r * NN))[tid + 256 * i];
    __builtin_amdgcn_sched_barrier(0);   // all 16 loads issue first (rule #18)
    unsigned int m[4] = {0, 0, 0, 0};
#pragma unroll
    for (int r = 0; r < 4; ++r)
#pragma unroll
        for (int i = 0; i < 4; ++i) {
            float4 q = v[r * 4 + i];
            m[r] |= ((q.x != 0.f) ? 1u : 0u) << (4 * i);
            m[r] |= ((q.y != 0.f) ? 1u : 0u) << (4 * i + 1);
            m[r] |= ((q.z != 0.f) ? 1u : 0u) << (4 * i + 2);
            m[r] |= ((q.w != 0.f) ? 1u : 0u) << (4 * i + 3);
        }
#pragma unroll
    for (int r = 0; r < 4; ++r)
        bits16[(size_t)(row0 + r) * 256 + tid] = (unsigned short)m[r];
}

__device__ __forceinline__ void wa_row(const float* __restrict__ Wf,
    const float* __restrict__ a1, const float* __restrict__ a2,
    float* __restrict__ wa1, float* __restrict__ wa2, int row, int lane) {
    const float* wr = Wf + (size_t)row * DOUT;
    float s1 = 0.f, s2 = 0.f;
    for (int k = lane; k < DOUT; k += 64) {
        float w = wr[k];
        s1 += w * a1[k];
        s2 += w * a2[k];
    }
    for (int off = 32; off; off >>= 1) {
        s1 += __shfl_down(s1, off);
        s2 += __shfl_down(s2, off);
    }
    if (lane == 0) { wa1[row] = s1; wa2[row] = s2; }
}

__device__ __forceinline__ void wt_unit(const float* __restrict__ W,
    unsigned short* __restrict__ wt, int idx, int tid) {
    int bx = idx & 7, gy = idx >> 3;
    int n = bx * 64 + (tid & 63);
    int g = gy * 4 + (tid >> 6);
    float v[8];
#pragma unroll
    for (int j = 0; j < 8; ++j) v[j] = W[(size_t)(g * 8 + j) * DOUT + n];
    union { unsigned short u[8]; uint4 q; } pk;
#pragma unroll
    for (int j = 0; j < 8; ++j) pk.u[j] = f2bf(v[j]);
    int sw = (n >> 1) & 3;
    int p  = (g & ~3) | ((g & 3) ^ sw);
    *(uint4*)(wt + (size_t)n * DIN + p * 8) = pk.q;
}

__device__ __forceinline__ void fx_row(const float* __restrict__ x,
    const float* __restrict__ wa1, const float* __restrict__ wa2,
    const float* __restrict__ b1, const float* __restrict__ b2,
    float* __restrict__ f1, float* __restrict__ f2,
    unsigned short* __restrict__ xb, int row, int lane) {
    const float* xr = x + (size_t)row * DIN + lane * 16;
    float xv[16];
    *(float4*)&xv[0]  = *(const float4*)(xr);
    *(float4*)&xv[4]  = *(const float4*)(xr + 4);
    *(float4*)&xv[8]  = *(const float4*)(xr + 8);
    *(float4*)&xv[12] = *(const float4*)(xr + 12);
    __builtin_amdgcn_sched_barrier(0);   // all 4 loads in flight
    const float* w1 = wa1 + lane * 16;
    const float* w2 = wa2 + lane * 16;
    float s1 = 0.f, s2 = 0.f;
#pragma unroll
    for (int j = 0; j < 16; ++j) {
        s1 += xv[j] * w1[j];
        s2 += xv[j] * w2[j];
    }
    union { unsigned short u[8]; uint4 q; } pk0, pk1;
#pragma unroll
    for (int j = 0; j < 8; ++j) { pk0.u[j] = f2bf(xv[j]); pk1.u[j] = f2bf(xv[8 + j]); }
    int sw = (row >> 1) & 3;
    int g0 = lane * 2, g1 = lane * 2 + 1;
    int p0 = (g0 & ~3) | ((g0 & 3) ^ sw);
    int p1 = (g1 & ~3) | ((g1 & 3) ^ sw);
    unsigned short* xrow = xb + (size_t)row * DIN;
    *(uint4*)(xrow + p0 * 8) = pk0.q;
    *(uint4*)(xrow + p1 * 8) = pk1.q;
    for (int off = 32; off; off >>= 1) {
        s1 += __shfl_down(s1, off);
        s2 += __shfl_down(s2, off);
    }
    if (lane == 0) { f1[row] = s1 + b1[0]; f2[row] = s2 + b2[0]; }
}

// ---------------- K1: mask rows [0,2048) | wt | wa  (1024 blocks)
__global__ __launch_bounds__(256) void k_p1(const float* __restrict__ adj,
    const float* __restrict__ W, const float* __restrict__ Wf,
    const float* __restrict__ a1, const float* __restrict__ a2,
    unsigned short* __restrict__ wt, float* __restrict__ wa1,
    float* __restrict__ wa2, unsigned short* __restrict__ bits16) {
    int tid = threadIdx.x, b = blockIdx.x;
    if (b < 512) {
        mask4(adj, bits16, b * 4, tid);
    } else if (b < 768) {
        wt_unit(W, wt, b - 512, tid);
    } else {
        wa_row(Wf, a1, a2, wa1, wa2, (b - 768) * 4 + (tid >> 6), tid & 63);
    }
}

// ---------------- K2: mask rows [2048,4096) | fx  (1536 blocks)
__global__ __launch_bounds__(256) void k_p2(const float* __restrict__ adj,
    const float* __restrict__ x,
    const float* __restrict__ wa1, const float* __restrict__ wa2,
    const float* __restrict__ b1, const float* __restrict__ b2,
    float* __restrict__ f1, float* __restrict__ f2,
    unsigned short* __restrict__ xb, unsigned short* __restrict__ bits16) {
    int tid = threadIdx.x, b = blockIdx.x;
    if (b < 512) {
        mask4(adj, bits16, 2048 + b * 4, tid);
    } else {
        fx_row(x, wa1, wa2, b1, b2, f1, f2, xb,
               (b - 512) * 4 + (tid >> 6), tid & 63);
    }
}

// ---------------- K3: Z via bitmask walk (wave per row, 4 rows/block) -> rZ
__global__ __launch_bounds__(256) void k_z(const unsigned long long* __restrict__ bits,
                                           const float* __restrict__ f1,
                                           const float* __restrict__ f2,
                                           float* __restrict__ rZ_out) {
    int row  = blockIdx.x * 4 + (threadIdx.x >> 6);
    int lane = threadIdx.x & 63;
    unsigned long long w = bits[(size_t)row * 64 + lane];
    float f1r = f1[row];
    float z = 0.f;
    while (w) {
        int b = __builtin_ctzll(w);
        w &= w - 1;
        int j = 16 * lane + 4 * (b >> 4) + 1024 * ((b >> 2) & 3) + (b & 3);
        float l = f1r + f2[j];
        z += __expf((l >= 0.f) ? l : ALPHA * l);
    }
    for (int off = 32; off; off >>= 1) z += __shfl_down(z, off);
    if (lane == 0) rZ_out[row] = 1.0f / z;
}

// ---------------- K4: colsum via bitmask walk (wave per row) -> s
__global__ __launch_bounds__(256) void k_s(const unsigned long long* __restrict__ bits,
                                           const float* __restrict__ f1,
                                           const float* __restrict__ f2,
                                           const float* __restrict__ rZ,
                                           float* __restrict__ s_out) {
    int row  = blockIdx.x * 4 + (threadIdx.x >> 6);
    int lane = threadIdx.x & 63;
    unsigned long long w = bits[(size_t)row * 64 + lane];
    float f2r = f2[row];
    float sum = 0.f;
    while (w) {
        int b = __builtin_ctzll(w);
        w &= w - 1;
        int j = 16 * lane + 4 * (b >> 4) + 1024 * ((b >> 2) & 3) + (b & 3);
        float l = f1[j] + f2r;
        float e = (l >= 0.f) ? l : ALPHA * l;
        sum += __expf(e) * rZ[j];
    }
    for (int off = 32; off; off >>= 1) sum += __shfl_down(sum, off);
    if (lane == 0) {
        float l   = f1[row] + f2r;
        float e   = (l >= 0.f) ? l : ALPHA * l;
        float cjj = __expf(e) * rZ[row];
        s_out[row] = (cjj + 1.0f) / (1.5f + 0.5f * sum);
    }
}

// ---------------- K5: gemm (round-18 counted-vmcnt T4 pipeline, unchanged)
__global__ __launch_bounds__(256) void k_gemm(const unsigned short* __restrict__ xb,
                                              const unsigned short* __restrict__ wt,
                                              const float* __restrict__ s,
                                              float* __restrict__ out) {
    __shared__ __align__(16) unsigned short As[3][64][32];
    __shared__ __align__(16) unsigned short Bs[3][64][32];
    int lid = blockIdx.y * gridDim.x + blockIdx.x;   // 0..511
    int xcd = lid & 7, idx = lid >> 3;               // idx 0..63
    int by = xcd * 8 + (idx & 7);                    // 0..63
    int bx = idx >> 3;                               // 0..7
    int bm = by * 64, bn = bx * 64;

    int tid = threadIdx.x, wid = tid >> 6, lane = tid & 63;
    int wr = wid >> 1, wc = wid & 1;                 // 2x2 wave grid of 32x32

    int srow = lane >> 2, sg = lane & 3;
    const unsigned short* ga0 = xb + (size_t)(bm + wid * 16 + srow) * DIN + sg * 8;
    const unsigned short* gb0 = wt + (size_t)(bn + wid * 16 + srow) * DIN + sg * 8;

    int r15 = lane & 15, gl = lane >> 4;
    int gofs = (gl ^ ((r15 >> 1) & 3)) * 8;          // XOR-swizzled read offset

    f32x4 acc[2][2] = {};

#define STAGE(BUF, K0) do {                                              \
        async16(ga0 + (K0), &As[BUF][wid * 16][0]);                      \
        async16(gb0 + (K0), &Bs[BUF][wid * 16][0]);                      \
    } while (0)

#define COMPUTE(BUF) do {                                                \
        const unsigned short* pa = &As[BUF][wr * 32 + r15][gofs];        \
        const unsigned short* pb = &Bs[BUF][wc * 32 + r15][gofs];        \
        short8 af0 = *(const short8*)(pa);                               \
        short8 af1 = *(const short8*)(pa + 16 * 32);                     \
        short8 bf0 = *(const short8*)(pb);                               \
        short8 bf1 = *(const short8*)(pb + 16 * 32);                     \
        acc[0][0] = __builtin_amdgcn_mfma_f32_16x16x32_bf16(af0, bf0, acc[0][0], 0, 0, 0); \
        acc[0][1] = __builtin_amdgcn_mfma_f32_16x16x32_bf16(af0, bf1, acc[0][1], 0, 0, 0); \
        acc[1][0] = __builtin_amdgcn_mfma_f32_16x16x32_bf16(af1, bf0, acc[1][0], 0, 0, 0); \
        acc[1][1] = __builtin_amdgcn_mfma_f32_16x16x32_bf16(af1, bf1, acc[1][1], 0, 0, 0); \
    } while (0)

#define WAITBAR(N) do {                                                  \
        asm volatile("s_waitcnt vmcnt(" #N ")" ::: "memory");            \
        __builtin_amdgcn_sched_barrier(0);                               \
        __builtin_amdgcn_s_barrier();                                    \
        __builtin_amdgcn_sched_barrier(0);                               \
    } while (0)

    STAGE(0, 0);
    STAGE(1, 32);
    for (int t = 0; t < 30; ++t) {
        WAITBAR(2);
        COMPUTE(t % 3);
        STAGE((t + 2) % 3, (t + 2) * 32);
    }
    WAITBAR(2);
    COMPUTE(0);
    WAITBAR(0);
    COMPUTE(1);

#pragma unroll
    for (int mi = 0; mi < 2; ++mi) {
        int crow0 = bm + wr * 32 + mi * 16 + gl * 4;
#pragma unroll
        for (int ni = 0; ni < 2; ++ni) {
            int ccol = bn + wc * 32 + ni * 16 + r15;
#pragma unroll
            for (int r = 0; r < 4; ++r) {
                int row = crow0 + r;
                float v = acc[mi][ni][r] * s[row];
                out[(size_t)row * DOUT + ccol] = fmaxf(v, 0.f);
            }
        }
    }
#undef STAGE
#undef COMPUTE
#undef WAITBAR
}

extern "C" void kernel_launch(void* const* d_in, const int* in_sizes, int n_in,
                              void* d_out, int out_size, void* d_ws, size_t ws_size,
                              hipStream_t stream) {
    const float* x   = (const float*)d_in[0];
    const float* adj = (const float*)d_in[1];
    const float* Wf  = (const float*)d_in[2];
    const float* a1  = (const float*)d_in[3];
    const float* b1  = (const float*)d_in[4];
    const float* a2  = (const float*)d_in[5];
    const float* b2  = (const float*)d_in[6];
    const float* W   = (const float*)d_in[7];
    float* out = (float*)d_out;

    char* w = (char*)d_ws;
    float* wa1 = (float*)(w + 0);
    float* wa2 = (float*)(w + 4096);
    float* f1  = (float*)(w + 16384);
    float* f2  = (float*)(w + 32768);
    float* rZ  = (float*)(w + 49152);
    float* s   = (float*)(w + 65536);
    unsigned short* bits16 = (unsigned short*)(w + 98304);           // 2 MB
    unsigned short* xb = (unsigned short*)(w + 2195456);             // 8 MB
    unsigned short* wt = (unsigned short*)(w + 10584064);            // 1 MB

    k_p1<<<1024, 256, 0, stream>>>(adj, W, Wf, a1, a2, wt, wa1, wa2, bits16);
    k_p2<<<1536, 256, 0, stream>>>(adj, x, wa1, wa2, b1, b2, f1, f2, xb, bits16);
    k_z<<<1024, 256, 0, stream>>>((const unsigned long long*)bits16, f1, f2, rZ);
    k_s<<<1024, 256, 0, stream>>>((const unsigned long long*)bits16, f1, f2, rZ, s);
    dim3 gg(8, 64);
    k_gemm<<<gg, 256, 0, stream>>>(xb, wt, s, out);
}